// Round 8
// baseline (1384.008 us; speedup 1.0000x reference)
//
#include <hip/hip_runtime.h>

// MHSA with relative position bias (Swin window attention), MI355X gfx950.
// B=2048 windows, N=49 tokens, C=1024, 16 heads x 64. fp16 MFMA, fp32 accum.
// Round 8: GEMMs = Round-2/7 schedule (best measured). Attention restructured:
//   - 2 waves per (b,h) block (wave w owns query rows [32w,32w+32)) ->
//     16KB LDS serves 2 waves -> 20 waves/CU (was 10); serial chains halved
//   - K frags read directly from global (same pattern as Q; no K staging)
//   - V transpose split by d across waves (32 scalar LDS writes/lane, was 64)
//   - bias table transposed [h][m][n], pre-scaled by log2(e); exp2f softmax
//     (identical math); bias loads become float4 (was scalar)

typedef _Float16 f16;
typedef _Float16 f16x8 __attribute__((ext_vector_type(8)));
typedef _Float16 f16x4 __attribute__((ext_vector_type(4)));
typedef float f32x4 __attribute__((ext_vector_type(4)));

#define G1P(p) ((const __attribute__((address_space(1))) unsigned int*)(p))
#define L3P(p) ((__attribute__((address_space(3))) unsigned int*)(p))

static const size_t MROW_MAX = 100351;   // clamp for padded rows 49..63 (attn)

// ---------------- fp32 -> fp16 convert (vec4) ----------------
__global__ void cvt_kernel(const float* __restrict__ in, f16* __restrict__ out, int n4) {
  int i = blockIdx.x * blockDim.x + threadIdx.x;
  int stride = gridDim.x * blockDim.x;
  const float4* in4 = (const float4*)in;
  f16x4* out4 = (f16x4*)out;
  for (; i < n4; i += stride) {
    float4 v = in4[i];
    f16x4 o = { (f16)v.x, (f16)v.y, (f16)v.z, (f16)v.w };
    out4[i] = o;
  }
}

// ---------------- bias table: bias_t[h][m][n] = log2e * bias(n,m), mask folded ----
__global__ void bias_kernel(const float* __restrict__ rpb, float* __restrict__ bias_t) {
  int h = blockIdx.x;
  for (int e = threadIdx.x; e < 4096; e += blockDim.x) {
    int m = e >> 6, n = e & 63;           // TRANSPOSED storage: [m][n]
    float v = -1e30f;
    if (n < 49 && m < 49) {
      int in_ = n / 7, jn = n % 7, im = m / 7, jm = m % 7;
      v = rpb[h * 169 + (im - in_ + 6) * 13 + (jm - jn + 6)];
    }
    bias_t[h * 4096 + e] = v * 1.44269504f;
  }
}

// ---------------- 256x256 8-phase GEMM (Round-2 verbatim; best measured) ----------
#define VM4 asm volatile("s_waitcnt vmcnt(4)" ::: "memory")
#define VM0 asm volatile("s_waitcnt vmcnt(0)" ::: "memory")
#define NOVM ((void)0)
#define NOSTG ((void)0)

#define STAGE(GB, ROW0, COL0, LDSOFF)                                              \
  {                                                                                \
    const f16* s0_ = (GB) + (size_t)((ROW0) + wid * 32 + srow) * K + ((COL0) + sce); \
    __builtin_amdgcn_global_load_lds(G1P(s0_), L3P(lds + (LDSOFF) + wid * 2048), 16, 0, 0); \
    const f16* s1_ = s0_ + (size_t)16 * K;                                         \
    __builtin_amdgcn_global_load_lds(G1P(s1_), L3P(lds + (LDSOFF) + wid * 2048 + 1024), 16, 0, 0); \
  }

#define MFMA4(AREG, ROW)                                                           \
  acc[ROW][0] = __builtin_amdgcn_mfma_f32_16x16x32_f16(AREG, b0, acc[ROW][0], 0, 0, 0); \
  acc[ROW][1] = __builtin_amdgcn_mfma_f32_16x16x32_f16(AREG, b1, acc[ROW][1], 0, 0, 0); \
  acc[ROW][2] = __builtin_amdgcn_mfma_f32_16x16x32_f16(AREG, b2, acc[ROW][2], 0, 0, 0); \
  acc[ROW][3] = __builtin_amdgcn_mfma_f32_16x16x32_f16(AREG, b3, acc[ROW][3], 0, 0, 0);

#define PHASE(ABASE, BBASE, MH, STG, VMW)                                          \
  {                                                                                \
    f16x8 a0 = *(const f16x8*)((ABASE) + (wm * 128 + (MH) * 64 +  0 + l15) * 64 + swz); \
    f16x8 a1 = *(const f16x8*)((ABASE) + (wm * 128 + (MH) * 64 + 16 + l15) * 64 + swz); \
    f16x8 a2 = *(const f16x8*)((ABASE) + (wm * 128 + (MH) * 64 + 32 + l15) * 64 + swz); \
    f16x8 a3 = *(const f16x8*)((ABASE) + (wm * 128 + (MH) * 64 + 48 + l15) * 64 + swz); \
    if ((MH) == 0) {                                                               \
      b0 = *(const f16x8*)((BBASE) + (wn * 64 +  0 + l15) * 64 + swz);             \
      b1 = *(const f16x8*)((BBASE) + (wn * 64 + 16 + l15) * 64 + swz);             \
      b2 = *(const f16x8*)((BBASE) + (wn * 64 + 32 + l15) * 64 + swz);             \
      b3 = *(const f16x8*)((BBASE) + (wn * 64 + 48 + l15) * 64 + swz);             \
    }                                                                              \
    STG;                                                                           \
    __builtin_amdgcn_s_barrier();                                                  \
    asm volatile("s_waitcnt lgkmcnt(0)" ::: "memory");                             \
    __builtin_amdgcn_sched_barrier(0);                                             \
    __builtin_amdgcn_s_setprio(1);                                                 \
    MFMA4(a0, (MH) * 4 + 0) MFMA4(a1, (MH) * 4 + 1)                                \
    MFMA4(a2, (MH) * 4 + 2) MFMA4(a3, (MH) * 4 + 3)                                \
    __builtin_amdgcn_s_setprio(0);                                                 \
    VMW;                                                                           \
    __builtin_amdgcn_s_barrier();                                                  \
  }

template <typename OutT>
__global__ __launch_bounds__(512, 2)
void gemm256(const f16* __restrict__ A, const f16* __restrict__ B,
             const float* __restrict__ bias, OutT* __restrict__ C,
             int N, int K, int ntiles_n) {
  __shared__ char lds[131072];
  const int tid = threadIdx.x;
  const int wid = tid >> 6, ln = tid & 63;
  const int l15 = ln & 15, lhi = ln >> 4;
  const int wm = wid >> 2, wn = wid & 3;
  const int srow = ln >> 2;
  const int sce = (((ln & 3) ^ ((ln >> 3) & 3)) << 3);
  const int swz = ((lhi ^ ((l15 >> 1) & 3)) << 4);

  const int nblk = gridDim.x;
  const int wg = (blockIdx.x & 7) * (nblk >> 3) + (blockIdx.x >> 3);
  const int bn = wg % ntiles_n, bm = wg / ntiles_n;
  const int m0 = bm * 256, n0 = bn * 256;

  f32x4 acc[8][4];
#pragma unroll
  for (int i = 0; i < 8; ++i)
#pragma unroll
    for (int j = 0; j < 4; ++j) acc[i][j] = (f32x4){0.f, 0.f, 0.f, 0.f};
  f16x8 b0, b1, b2, b3;

  STAGE(A, m0, 0, 0);
  STAGE(B, n0, 0, 32768);
  STAGE(A, m0, 32, 16384);
  STAGE(B, n0, 32, 49152);
  STAGE(A, m0, 64, 65536);
  STAGE(B, n0, 64, 98304);
  VM4;
  __builtin_amdgcn_s_barrier();

  for (int i = 0; i < 7; ++i) {
    const int cT1k1 = (2 * i + 1) * 64 + 32;
    const int cT2k0 = (2 * i + 2) * 64;
    const int cT2k1 = cT2k0 + 32;
    const int cT3k0 = (2 * i + 3) * 64;
    PHASE(lds + 0,      lds + 32768,  0, STAGE(A, m0, cT1k1, 81920),  NOVM);
    PHASE(lds + 0,      lds + 32768,  1, STAGE(B, n0, cT1k1, 114688), NOVM);
    PHASE(lds + 16384,  lds + 49152,  0, STAGE(A, m0, cT2k0, 0),      NOVM);
    PHASE(lds + 16384,  lds + 49152,  1, STAGE(B, n0, cT2k0, 32768),  VM4);
    PHASE(lds + 65536,  lds + 98304,  0, STAGE(A, m0, cT2k1, 16384),  NOVM);
    PHASE(lds + 65536,  lds + 98304,  1, STAGE(B, n0, cT2k1, 49152),  NOVM);
    PHASE(lds + 81920,  lds + 114688, 0, STAGE(A, m0, cT3k0, 65536),  NOVM);
    PHASE(lds + 81920,  lds + 114688, 1, STAGE(B, n0, cT3k0, 98304),  VM4);
  }
  PHASE(lds + 0,      lds + 32768,  0, STAGE(A, m0, 15 * 64 + 32, 81920),  NOVM);
  PHASE(lds + 0,      lds + 32768,  1, STAGE(B, n0, 15 * 64 + 32, 114688), NOVM);
  PHASE(lds + 16384,  lds + 49152,  0, NOSTG, NOVM);
  PHASE(lds + 16384,  lds + 49152,  1, NOSTG, VM0);
  PHASE(lds + 65536,  lds + 98304,  0, NOSTG, NOVM);
  PHASE(lds + 65536,  lds + 98304,  1, NOSTG, NOVM);
  PHASE(lds + 81920,  lds + 114688, 0, NOSTG, NOVM);
  PHASE(lds + 81920,  lds + 114688, 1, NOSTG, NOVM);

  float bv[4];
#pragma unroll
  for (int j = 0; j < 4; ++j) bv[j] = bias[n0 + wn * 64 + j * 16 + l15];
#pragma unroll
  for (int ii = 0; ii < 8; ++ii)
#pragma unroll
    for (int j = 0; j < 4; ++j)
#pragma unroll
      for (int r = 0; r < 4; ++r) {
        int gr = m0 + wm * 128 + ii * 16 + lhi * 4 + r;
        int gc = n0 + wn * 64 + j * 16 + l15;
        C[(size_t)gr * N + gc] = (OutT)(acc[ii][j][r] + bv[j]);
      }
}

// ---------------- attention: 2 waves per (window, head) ----------------
// LDS 16KB: P [0,8K), Vt [8K,16K). Wave w owns query rows [32w, 32w+32).
// K frags direct from global. One barrier (after V transpose).
__global__ __launch_bounds__(128, 4)
void attn_kernel(const f16* __restrict__ qkv,        // [MTOT][3072] q|k|v
                 const float* __restrict__ bias_t,   // [16][m][n], pre-scaled log2e
                 f16* __restrict__ out) {             // [MTOT][1024]
  __shared__ char lds[16384];
  const int bh = blockIdx.x;
  const int b = bh >> 4, h = bh & 15;
  const int tid = threadIdx.x;
  const int w = tid >> 6;             // wave 0..1
  const int ln = tid & 63;
  const int l15 = ln & 15, lhi = ln >> 4;
  const size_t base = (size_t)b * 49;
  const int nbase = w * 32;

  // Q frags (A-operand): rows nbase + t*16 + l15
  f16x8 qf[2][2];
#pragma unroll
  for (int t = 0; t < 2; ++t) {
    size_t row = base + nbase + t * 16 + l15;
    if (row > MROW_MAX) row = MROW_MAX;
    const f16* qp = qkv + row * 3072 + h * 64 + lhi * 8;
    qf[t][0] = *(const f16x8*)(qp);
    qf[t][1] = *(const f16x8*)(qp + 32);
  }

  // V transpose: lane owns V row m=ln, d-columns [nbase, nbase+32)
  {
    size_t row = base + ln;
    if (row > MROW_MAX) row = MROW_MAX;
    const f16* vp = qkv + row * 3072 + 2048 + h * 64 + nbase;
    f16x8 vr[4];
#pragma unroll
    for (int j = 0; j < 4; ++j) vr[j] = *(const f16x8*)(vp + j * 8);
#pragma unroll
    for (int dd = 0; dd < 32; ++dd) {
      int d = nbase + dd;
      *(f16*)(lds + 8192 + d * 128 + ((ln * 2) ^ ((d & 7) << 4))) = vr[dd >> 3][dd & 7];
    }
  }

  // S = Q @ K^T  (K B-frags direct from global: row m = t*16+l15)
  f32x4 acc[2][4];
#pragma unroll
  for (int i = 0; i < 2; ++i)
#pragma unroll
    for (int j = 0; j < 4; ++j) acc[i][j] = (f32x4){0.f, 0.f, 0.f, 0.f};
#pragma unroll
  for (int kk = 0; kk < 2; ++kk) {
    f16x8 bf[4];
#pragma unroll
    for (int t = 0; t < 4; ++t) {
      size_t row = base + t * 16 + l15;
      if (row > MROW_MAX) row = MROW_MAX;
      bf[t] = *(const f16x8*)(qkv + row * 3072 + 1024 + h * 64 + kk * 32 + lhi * 8);
    }
#pragma unroll
    for (int i = 0; i < 2; ++i)
#pragma unroll
      for (int j = 0; j < 4; ++j)
        acc[i][j] = __builtin_amdgcn_mfma_f32_16x16x32_f16(qf[i][kk], bf[j], acc[i][j], 0, 0, 0);
  }

  __syncthreads();   // Vt complete (both waves)

  // softmax (base-2, logits pre-scaled by log2e; identical result)
  const float SC = 0.125f * 1.44269504f;
  const float* bb = bias_t + h * 4096;
#pragma unroll
  for (int i = 0; i < 2; ++i) {
    float4 bq[4];
#pragma unroll
    for (int j = 0; j < 4; ++j)
      bq[j] = *(const float4*)(bb + (j * 16 + l15) * 64 + nbase + i * 16 + lhi * 4);
#pragma unroll
    for (int r = 0; r < 4; ++r) {
      int n = nbase + i * 16 + lhi * 4 + r;
      float lv[4];
#pragma unroll
      for (int j = 0; j < 4; ++j)
        lv[j] = acc[i][j][r] * SC + ((const float*)&bq[j])[r];
      float Mx = fmaxf(fmaxf(lv[0], lv[1]), fmaxf(lv[2], lv[3]));
#pragma unroll
      for (int off = 1; off < 16; off <<= 1) Mx = fmaxf(Mx, __shfl_xor(Mx, off));
      float s = 0.f;
#pragma unroll
      for (int j = 0; j < 4; ++j) { lv[j] = exp2f(lv[j] - Mx); s += lv[j]; }
#pragma unroll
      for (int off = 1; off < 16; off <<= 1) s += __shfl_xor(s, off);
      float inv = 1.f / s;
#pragma unroll
      for (int j = 0; j < 4; ++j) {
        int m = j * 16 + l15;
        *(f16*)(lds + n * 128 + ((m * 2) ^ ((n & 7) << 4))) = (f16)(lv[j] * inv);
      }
    }
  }
  // P rows are own-wave; Vt already synced -> no second barrier needed

  // O = P @ V
  f32x4 o[2][4];
#pragma unroll
  for (int i = 0; i < 2; ++i)
#pragma unroll
    for (int j = 0; j < 4; ++j) o[i][j] = (f32x4){0.f, 0.f, 0.f, 0.f};
#pragma unroll
  for (int kk = 0; kk < 2; ++kk) {
    f16x8 af[2], bf[4];
#pragma unroll
    for (int t = 0; t < 2; ++t) {
      int nr = nbase + t * 16 + l15;
      af[t] = *(const f16x8*)(lds + nr * 128 + ((kk * 64 + lhi * 16) ^ ((nr & 7) << 4)));
    }
#pragma unroll
    for (int u = 0; u < 4; ++u) {
      int dr = u * 16 + l15;
      bf[u] = *(const f16x8*)(lds + 8192 + dr * 128 + ((kk * 64 + lhi * 16) ^ ((dr & 7) << 4)));
    }
#pragma unroll
    for (int i = 0; i < 2; ++i)
#pragma unroll
      for (int j = 0; j < 4; ++j)
        o[i][j] = __builtin_amdgcn_mfma_f32_16x16x32_f16(af[i], bf[j], o[i][j], 0, 0, 0);
  }
#pragma unroll
  for (int i = 0; i < 2; ++i)
#pragma unroll
    for (int j = 0; j < 4; ++j)
#pragma unroll
      for (int r = 0; r < 4; ++r) {
        int n = nbase + i * 16 + lhi * 4 + r;
        if (n < 49)
          out[(base + n) * 1024 + h * 64 + j * 16 + l15] = (f16)o[i][j][r];
      }
}

extern "C" void kernel_launch(void* const* d_in, const int* in_sizes, int n_in,
                              void* d_out, int out_size, void* d_ws, size_t ws_size,
                              hipStream_t stream) {
  const float* x      = (const float*)d_in[0];  // [100352][1024]
  const float* qkv_w  = (const float*)d_in[1];  // [3072][1024]
  const float* qkv_b  = (const float*)d_in[2];  // [3072]
  const float* rpb    = (const float*)d_in[3];  // [16][13][13]
  const float* proj_w = (const float*)d_in[4];  // [1024][1024]
  const float* proj_b = (const float*)d_in[5];  // [1024]
  float* out = (float*)d_out;

  char* ws = (char*)d_ws;
  f16*   x16      = (f16*)(ws);                              // 205,520,896
  f16*   wq16     = (f16*)(ws + 205520896);                  //   6,291,456
  f16*   wp16     = (f16*)(ws + 211812352);                  //   2,097,152
  f16*   qkv16    = (f16*)(ws + 213909504);                  // 616,562,688
  f16*   attn16   = (f16*)(ws + 830472192);                  // 205,520,896
  float* bias_t   = (float*)(ws + 1035993088);               //     262,144

  cvt_kernel<<<2048, 256, 0, stream>>>(x, x16, 102760448 / 4);
  cvt_kernel<<<1024, 256, 0, stream>>>(qkv_w, wq16, 3145728 / 4);
  cvt_kernel<<<512, 256, 0, stream>>>(proj_w, wp16, 1048576 / 4);
  bias_kernel<<<16, 64, 0, stream>>>(rpb, bias_t);

  // qkv = x @ qkv_w^T + qkv_b   [100352][3072] fp16   (392 x 12 tiles)
  gemm256<f16><<<4704, 512, 0, stream>>>(x16, wq16, qkv_b, qkv16, 3072, 1024, 12);
  // attention: 2 waves per (window, head)
  attn_kernel<<<2048 * 16, 128, 0, stream>>>(qkv16, bias_t, attn16);
  // out = attn @ proj_w^T + proj_b   [100352][1024] fp32  (392 x 4 tiles)
  gemm256<float><<<1568, 512, 0, stream>>>(attn16, wp16, proj_b, out, 1024, 1024, 4);
}

// Round 9
// 1383.052 us; speedup vs baseline: 1.0007x; 1.0007x over previous
//
#include <hip/hip_runtime.h>

// MHSA with relative position bias (Swin window attention), MI355X gfx950.
// B=2048 windows, N=49 tokens, C=1024, 16 heads x 64. fp16 MFMA, fp32 accum.
// Round 9: GEMMs = Round-2/7 schedule (best measured). Attention: R7's proven
// K-staging (global_load_lds at start, QK^T from LDS, P overwrites K) with
// 4 waves per (b,h) block: wave w owns query rows [16w,16w+16).
//   LDS 16KB/block -> 8 blocks x 4 waves = up to 32 waves/CU (R7: 10).
//   Serial chains quartered; extra barrier between QK^T and P-overwrite.
//   bias_t[h][m][n] pre-scaled log2e + exp2f softmax (R8, correctness-proven).

typedef _Float16 f16;
typedef _Float16 f16x8 __attribute__((ext_vector_type(8)));
typedef _Float16 f16x4 __attribute__((ext_vector_type(4)));
typedef float f32x4 __attribute__((ext_vector_type(4)));

#define G1P(p) ((const __attribute__((address_space(1))) unsigned int*)(p))
#define L3P(p) ((__attribute__((address_space(3))) unsigned int*)(p))

static const size_t MROW_MAX = 100351;   // clamp for padded rows 49..63 (attn)

// ---------------- fp32 -> fp16 convert (vec4) ----------------
__global__ void cvt_kernel(const float* __restrict__ in, f16* __restrict__ out, int n4) {
  int i = blockIdx.x * blockDim.x + threadIdx.x;
  int stride = gridDim.x * blockDim.x;
  const float4* in4 = (const float4*)in;
  f16x4* out4 = (f16x4*)out;
  for (; i < n4; i += stride) {
    float4 v = in4[i];
    f16x4 o = { (f16)v.x, (f16)v.y, (f16)v.z, (f16)v.w };
    out4[i] = o;
  }
}

// ---------------- bias table: bias_t[h][m][n] = log2e * bias(n,m), mask folded ----
__global__ void bias_kernel(const float* __restrict__ rpb, float* __restrict__ bias_t) {
  int h = blockIdx.x;
  for (int e = threadIdx.x; e < 4096; e += blockDim.x) {
    int m = e >> 6, n = e & 63;           // TRANSPOSED storage: [m][n]
    float v = -1e30f;
    if (n < 49 && m < 49) {
      int in_ = n / 7, jn = n % 7, im = m / 7, jm = m % 7;
      v = rpb[h * 169 + (im - in_ + 6) * 13 + (jm - jn + 6)];
    }
    bias_t[h * 4096 + e] = v * 1.44269504f;
  }
}

// ---------------- 256x256 8-phase GEMM (Round-2 verbatim; best measured) ----------
#define VM4 asm volatile("s_waitcnt vmcnt(4)" ::: "memory")
#define VM0 asm volatile("s_waitcnt vmcnt(0)" ::: "memory")
#define NOVM ((void)0)
#define NOSTG ((void)0)

#define STAGE(GB, ROW0, COL0, LDSOFF)                                              \
  {                                                                                \
    const f16* s0_ = (GB) + (size_t)((ROW0) + wid * 32 + srow) * K + ((COL0) + sce); \
    __builtin_amdgcn_global_load_lds(G1P(s0_), L3P(lds + (LDSOFF) + wid * 2048), 16, 0, 0); \
    const f16* s1_ = s0_ + (size_t)16 * K;                                         \
    __builtin_amdgcn_global_load_lds(G1P(s1_), L3P(lds + (LDSOFF) + wid * 2048 + 1024), 16, 0, 0); \
  }

#define MFMA4(AREG, ROW)                                                           \
  acc[ROW][0] = __builtin_amdgcn_mfma_f32_16x16x32_f16(AREG, b0, acc[ROW][0], 0, 0, 0); \
  acc[ROW][1] = __builtin_amdgcn_mfma_f32_16x16x32_f16(AREG, b1, acc[ROW][1], 0, 0, 0); \
  acc[ROW][2] = __builtin_amdgcn_mfma_f32_16x16x32_f16(AREG, b2, acc[ROW][2], 0, 0, 0); \
  acc[ROW][3] = __builtin_amdgcn_mfma_f32_16x16x32_f16(AREG, b3, acc[ROW][3], 0, 0, 0);

#define PHASE(ABASE, BBASE, MH, STG, VMW)                                          \
  {                                                                                \
    f16x8 a0 = *(const f16x8*)((ABASE) + (wm * 128 + (MH) * 64 +  0 + l15) * 64 + swz); \
    f16x8 a1 = *(const f16x8*)((ABASE) + (wm * 128 + (MH) * 64 + 16 + l15) * 64 + swz); \
    f16x8 a2 = *(const f16x8*)((ABASE) + (wm * 128 + (MH) * 64 + 32 + l15) * 64 + swz); \
    f16x8 a3 = *(const f16x8*)((ABASE) + (wm * 128 + (MH) * 64 + 48 + l15) * 64 + swz); \
    if ((MH) == 0) {                                                               \
      b0 = *(const f16x8*)((BBASE) + (wn * 64 +  0 + l15) * 64 + swz);             \
      b1 = *(const f16x8*)((BBASE) + (wn * 64 + 16 + l15) * 64 + swz);             \
      b2 = *(const f16x8*)((BBASE) + (wn * 64 + 32 + l15) * 64 + swz);             \
      b3 = *(const f16x8*)((BBASE) + (wn * 64 + 48 + l15) * 64 + swz);             \
    }                                                                              \
    STG;                                                                           \
    __builtin_amdgcn_s_barrier();                                                  \
    asm volatile("s_waitcnt lgkmcnt(0)" ::: "memory");                             \
    __builtin_amdgcn_sched_barrier(0);                                             \
    __builtin_amdgcn_s_setprio(1);                                                 \
    MFMA4(a0, (MH) * 4 + 0) MFMA4(a1, (MH) * 4 + 1)                                \
    MFMA4(a2, (MH) * 4 + 2) MFMA4(a3, (MH) * 4 + 3)                                \
    __builtin_amdgcn_s_setprio(0);                                                 \
    VMW;                                                                           \
    __builtin_amdgcn_s_barrier();                                                  \
  }

template <typename OutT>
__global__ __launch_bounds__(512, 2)
void gemm256(const f16* __restrict__ A, const f16* __restrict__ B,
             const float* __restrict__ bias, OutT* __restrict__ C,
             int N, int K, int ntiles_n) {
  __shared__ char lds[131072];
  const int tid = threadIdx.x;
  const int wid = tid >> 6, ln = tid & 63;
  const int l15 = ln & 15, lhi = ln >> 4;
  const int wm = wid >> 2, wn = wid & 3;
  const int srow = ln >> 2;
  const int sce = (((ln & 3) ^ ((ln >> 3) & 3)) << 3);
  const int swz = ((lhi ^ ((l15 >> 1) & 3)) << 4);

  const int nblk = gridDim.x;
  const int wg = (blockIdx.x & 7) * (nblk >> 3) + (blockIdx.x >> 3);
  const int bn = wg % ntiles_n, bm = wg / ntiles_n;
  const int m0 = bm * 256, n0 = bn * 256;

  f32x4 acc[8][4];
#pragma unroll
  for (int i = 0; i < 8; ++i)
#pragma unroll
    for (int j = 0; j < 4; ++j) acc[i][j] = (f32x4){0.f, 0.f, 0.f, 0.f};
  f16x8 b0, b1, b2, b3;

  STAGE(A, m0, 0, 0);
  STAGE(B, n0, 0, 32768);
  STAGE(A, m0, 32, 16384);
  STAGE(B, n0, 32, 49152);
  STAGE(A, m0, 64, 65536);
  STAGE(B, n0, 64, 98304);
  VM4;
  __builtin_amdgcn_s_barrier();

  for (int i = 0; i < 7; ++i) {
    const int cT1k1 = (2 * i + 1) * 64 + 32;
    const int cT2k0 = (2 * i + 2) * 64;
    const int cT2k1 = cT2k0 + 32;
    const int cT3k0 = (2 * i + 3) * 64;
    PHASE(lds + 0,      lds + 32768,  0, STAGE(A, m0, cT1k1, 81920),  NOVM);
    PHASE(lds + 0,      lds + 32768,  1, STAGE(B, n0, cT1k1, 114688), NOVM);
    PHASE(lds + 16384,  lds + 49152,  0, STAGE(A, m0, cT2k0, 0),      NOVM);
    PHASE(lds + 16384,  lds + 49152,  1, STAGE(B, n0, cT2k0, 32768),  VM4);
    PHASE(lds + 65536,  lds + 98304,  0, STAGE(A, m0, cT2k1, 16384),  NOVM);
    PHASE(lds + 65536,  lds + 98304,  1, STAGE(B, n0, cT2k1, 49152),  NOVM);
    PHASE(lds + 81920,  lds + 114688, 0, STAGE(A, m0, cT3k0, 65536),  NOVM);
    PHASE(lds + 81920,  lds + 114688, 1, STAGE(B, n0, cT3k0, 98304),  VM4);
  }
  PHASE(lds + 0,      lds + 32768,  0, STAGE(A, m0, 15 * 64 + 32, 81920),  NOVM);
  PHASE(lds + 0,      lds + 32768,  1, STAGE(B, n0, 15 * 64 + 32, 114688), NOVM);
  PHASE(lds + 16384,  lds + 49152,  0, NOSTG, NOVM);
  PHASE(lds + 16384,  lds + 49152,  1, NOSTG, VM0);
  PHASE(lds + 65536,  lds + 98304,  0, NOSTG, NOVM);
  PHASE(lds + 65536,  lds + 98304,  1, NOSTG, NOVM);
  PHASE(lds + 81920,  lds + 114688, 0, NOSTG, NOVM);
  PHASE(lds + 81920,  lds + 114688, 1, NOSTG, NOVM);

  float bv[4];
#pragma unroll
  for (int j = 0; j < 4; ++j) bv[j] = bias[n0 + wn * 64 + j * 16 + l15];
#pragma unroll
  for (int ii = 0; ii < 8; ++ii)
#pragma unroll
    for (int j = 0; j < 4; ++j)
#pragma unroll
      for (int r = 0; r < 4; ++r) {
        int gr = m0 + wm * 128 + ii * 16 + lhi * 4 + r;
        int gc = n0 + wn * 64 + j * 16 + l15;
        C[(size_t)gr * N + gc] = (OutT)(acc[ii][j][r] + bv[j]);
      }
}

// ---------------- attention: 4 waves per (window, head) ----------------
// LDS 16KB: K then P [0,8K), Vt [8K,16K). Wave w owns query rows [16w,16w+16).
// K staged via global_load_lds (2 slots/wave); barrier1 = K+Vt ready;
// barrier2 = all K reads done before P overwrites K's buffer.
__global__ __launch_bounds__(256, 4)
void attn_kernel(const f16* __restrict__ qkv,        // [MTOT][3072] q|k|v
                 const float* __restrict__ bias_t,   // [16][m][n], pre-scaled log2e
                 f16* __restrict__ out) {             // [MTOT][1024]
  __shared__ char lds[16384];
  const int bh = blockIdx.x;
  const int b = bh >> 4, h = bh & 15;
  const int tid = threadIdx.x;
  const int w = tid >> 6;             // wave 0..3
  const int ln = tid & 63;
  const int l15 = ln & 15, lhi = ln >> 4;
  const size_t base = (size_t)b * 49;
  const int nbase = w * 16;

  // K staging: wave w stages slots 2w, 2w+1 (rows [16w, 16w+16))
  {
    int rA = ln >> 3, lc = ln & 7;
#pragma unroll
    for (int cc = 0; cc < 2; ++cc) {
      int c = w * 2 + cc;
      int r = c * 8 + rA;
      int ce = (lc ^ (r & 7)) << 3;
      size_t row = base + r;
      if (row > MROW_MAX) row = MROW_MAX;
      const f16* g = qkv + row * 3072 + 1024 + h * 64 + ce;
      __builtin_amdgcn_global_load_lds(G1P(g), L3P(lds + c * 1024), 16, 0, 0);
    }
  }

  // Q frags (A-operand): rows nbase + l15
  f16x8 qf[2];
  {
    size_t row = base + nbase + l15;
    if (row > MROW_MAX) row = MROW_MAX;
    const f16* qp = qkv + row * 3072 + h * 64 + lhi * 8;
    qf[0] = *(const f16x8*)(qp);
    qf[1] = *(const f16x8*)(qp + 32);
  }

  // V transpose: lane owns V row m=ln, d-columns [nbase, nbase+16)
  {
    size_t row = base + ln;
    if (row > MROW_MAX) row = MROW_MAX;
    const f16* vp = qkv + row * 3072 + 2048 + h * 64 + nbase;
    f16x8 vr[2];
    vr[0] = *(const f16x8*)(vp);
    vr[1] = *(const f16x8*)(vp + 8);
#pragma unroll
    for (int dd = 0; dd < 16; ++dd) {
      int d = nbase + dd;
      *(f16*)(lds + 8192 + d * 128 + ((ln * 2) ^ ((d & 7) << 4))) = vr[dd >> 3][dd & 7];
    }
  }

  __syncthreads();   // K staged + Vt complete

  // S = Q @ K^T  (K B-frags from LDS)
  f32x4 acc[4];
#pragma unroll
  for (int j = 0; j < 4; ++j) acc[j] = (f32x4){0.f, 0.f, 0.f, 0.f};
#pragma unroll
  for (int kk = 0; kk < 2; ++kk) {
    f16x8 bf[4];
#pragma unroll
    for (int t = 0; t < 4; ++t) {
      int mr = t * 16 + l15;
      int pb = (kk * 64 + lhi * 16) ^ ((mr & 7) << 4);
      bf[t] = *(const f16x8*)(lds + mr * 128 + pb);
    }
#pragma unroll
    for (int j = 0; j < 4; ++j)
      acc[j] = __builtin_amdgcn_mfma_f32_16x16x32_f16(qf[kk], bf[j], acc[j], 0, 0, 0);
  }

  __syncthreads();   // all waves done reading K -> P may overwrite

  // softmax (base-2; logits pre-scaled by log2e)
  const float SC = 0.125f * 1.44269504f;
  const float* bb = bias_t + h * 4096;
  {
    float4 bq[4];
#pragma unroll
    for (int j = 0; j < 4; ++j)
      bq[j] = *(const float4*)(bb + (j * 16 + l15) * 64 + nbase + lhi * 4);
#pragma unroll
    for (int r = 0; r < 4; ++r) {
      int n = nbase + lhi * 4 + r;
      float lv[4];
#pragma unroll
      for (int j = 0; j < 4; ++j)
        lv[j] = acc[j][r] * SC + ((const float*)&bq[j])[r];
      float Mx = fmaxf(fmaxf(lv[0], lv[1]), fmaxf(lv[2], lv[3]));
#pragma unroll
      for (int off = 1; off < 16; off <<= 1) Mx = fmaxf(Mx, __shfl_xor(Mx, off));
      float s = 0.f;
#pragma unroll
      for (int j = 0; j < 4; ++j) { lv[j] = exp2f(lv[j] - Mx); s += lv[j]; }
#pragma unroll
      for (int off = 1; off < 16; off <<= 1) s += __shfl_xor(s, off);
      float inv = 1.f / s;
#pragma unroll
      for (int j = 0; j < 4; ++j) {
        int m = j * 16 + l15;
        *(f16*)(lds + n * 128 + ((m * 2) ^ ((n & 7) << 4))) = (f16)(lv[j] * inv);
      }
    }
  }
  // PV reads only own P rows (written by this wave, in-order DS) + Vt (barrier1)

  // O = P @ V
  f32x4 o[4];
#pragma unroll
  for (int j = 0; j < 4; ++j) o[j] = (f32x4){0.f, 0.f, 0.f, 0.f};
#pragma unroll
  for (int kk = 0; kk < 2; ++kk) {
    f16x8 af, bf[4];
    {
      int nr = nbase + l15;
      af = *(const f16x8*)(lds + nr * 128 + ((kk * 64 + lhi * 16) ^ ((nr & 7) << 4)));
    }
#pragma unroll
    for (int u = 0; u < 4; ++u) {
      int dr = u * 16 + l15;
      bf[u] = *(const f16x8*)(lds + 8192 + dr * 128 + ((kk * 64 + lhi * 16) ^ ((dr & 7) << 4)));
    }
#pragma unroll
    for (int j = 0; j < 4; ++j)
      o[j] = __builtin_amdgcn_mfma_f32_16x16x32_f16(af, bf[j], o[j], 0, 0, 0);
  }
#pragma unroll
  for (int j = 0; j < 4; ++j)
#pragma unroll
    for (int r = 0; r < 4; ++r) {
      int n = nbase + lhi * 4 + r;
      if (n < 49)
        out[(base + n) * 1024 + h * 64 + j * 16 + l15] = (f16)o[j][r];
    }
}

extern "C" void kernel_launch(void* const* d_in, const int* in_sizes, int n_in,
                              void* d_out, int out_size, void* d_ws, size_t ws_size,
                              hipStream_t stream) {
  const float* x      = (const float*)d_in[0];  // [100352][1024]
  const float* qkv_w  = (const float*)d_in[1];  // [3072][1024]
  const float* qkv_b  = (const float*)d_in[2];  // [3072]
  const float* rpb    = (const float*)d_in[3];  // [16][13][13]
  const float* proj_w = (const float*)d_in[4];  // [1024][1024]
  const float* proj_b = (const float*)d_in[5];  // [1024]
  float* out = (float*)d_out;

  char* ws = (char*)d_ws;
  f16*   x16      = (f16*)(ws);                              // 205,520,896
  f16*   wq16     = (f16*)(ws + 205520896);                  //   6,291,456
  f16*   wp16     = (f16*)(ws + 211812352);                  //   2,097,152
  f16*   qkv16    = (f16*)(ws + 213909504);                  // 616,562,688
  f16*   attn16   = (f16*)(ws + 830472192);                  // 205,520,896
  float* bias_t   = (float*)(ws + 1035993088);               //     262,144

  cvt_kernel<<<2048, 256, 0, stream>>>(x, x16, 102760448 / 4);
  cvt_kernel<<<1024, 256, 0, stream>>>(qkv_w, wq16, 3145728 / 4);
  cvt_kernel<<<512, 256, 0, stream>>>(proj_w, wp16, 1048576 / 4);
  bias_kernel<<<16, 64, 0, stream>>>(rpb, bias_t);

  // qkv = x @ qkv_w^T + qkv_b   [100352][3072] fp16   (392 x 12 tiles)
  gemm256<f16><<<4704, 512, 0, stream>>>(x16, wq16, qkv_b, qkv16, 3072, 1024, 12);
  // attention: 4 waves per (window, head)
  attn_kernel<<<2048 * 16, 256, 0, stream>>>(qkv16, bias_t, attn16);
  // out = attn @ proj_w^T + proj_b   [100352][1024] fp32  (392 x 4 tiles)
  gemm256<float><<<1568, 512, 0, stream>>>(attn16, wp16, proj_b, out, 1024, 1024, 4);
}

// Round 10
// 1320.999 us; speedup vs baseline: 1.0477x; 1.0470x over previous
//
#include <hip/hip_runtime.h>

// MHSA with relative position bias (Swin window attention), MI355X gfx950.
// B=2048 windows, N=49 tokens, C=1024, 16 heads x 64. fp16 MFMA, fp32 accum.
// Round 10: GEMMs = Round-2/7 schedule (settled: 670us, 43% MfmaUtil).
// Attention rebuilt latency-first: 1 wave/block, ZERO barriers (per-wave
// in-order DS + one vmcnt(0) drain), ALL global loads hoisted to the top
// (K global_load_lds, V, Q, bias -- ~28 VMEM in flight), f16 bias table
// [h][m][n] pre-scaled log2e loaded as f16x4 (kills R7's 64 mid-softmax
// scalar loads), exp2f softmax, setprio around MFMA. LDS 16KB -> 10 blk/CU,
// each an independent memory stream.

typedef _Float16 f16;
typedef _Float16 f16x8 __attribute__((ext_vector_type(8)));
typedef _Float16 f16x4 __attribute__((ext_vector_type(4)));
typedef float f32x4 __attribute__((ext_vector_type(4)));

#define G1P(p) ((const __attribute__((address_space(1))) unsigned int*)(p))
#define L3P(p) ((__attribute__((address_space(3))) unsigned int*)(p))

static const size_t MROW_MAX = 100351;   // clamp for padded rows 49..63 (attn)

// ---------------- fp32 -> fp16 convert (vec4) ----------------
__global__ void cvt_kernel(const float* __restrict__ in, f16* __restrict__ out, int n4) {
  int i = blockIdx.x * blockDim.x + threadIdx.x;
  int stride = gridDim.x * blockDim.x;
  const float4* in4 = (const float4*)in;
  f16x4* out4 = (f16x4*)out;
  for (; i < n4; i += stride) {
    float4 v = in4[i];
    f16x4 o = { (f16)v.x, (f16)v.y, (f16)v.z, (f16)v.w };
    out4[i] = o;
  }
}

// ---------------- bias table: f16 bias_t[h][m][n] = log2e*bias(n,m); mask=-60000 ----
__global__ void bias_kernel(const float* __restrict__ rpb, f16* __restrict__ bias_t) {
  int h = blockIdx.x;
  for (int e = threadIdx.x; e < 4096; e += blockDim.x) {
    int m = e >> 6, n = e & 63;           // TRANSPOSED storage: [m][n]
    float v = -60000.f;                   // exp2(x-60000) == 0 in f32
    if (n < 49 && m < 49) {
      int in_ = n / 7, jn = n % 7, im = m / 7, jm = m % 7;
      v = rpb[h * 169 + (im - in_ + 6) * 13 + (jm - jn + 6)] * 1.44269504f;
    }
    bias_t[h * 4096 + e] = (f16)v;
  }
}

// ---------------- 256x256 8-phase GEMM (Round-2 verbatim; best measured) ----------
#define VM4 asm volatile("s_waitcnt vmcnt(4)" ::: "memory")
#define VM0 asm volatile("s_waitcnt vmcnt(0)" ::: "memory")
#define NOVM ((void)0)
#define NOSTG ((void)0)

#define STAGE(GB, ROW0, COL0, LDSOFF)                                              \
  {                                                                                \
    const f16* s0_ = (GB) + (size_t)((ROW0) + wid * 32 + srow) * K + ((COL0) + sce); \
    __builtin_amdgcn_global_load_lds(G1P(s0_), L3P(lds + (LDSOFF) + wid * 2048), 16, 0, 0); \
    const f16* s1_ = s0_ + (size_t)16 * K;                                         \
    __builtin_amdgcn_global_load_lds(G1P(s1_), L3P(lds + (LDSOFF) + wid * 2048 + 1024), 16, 0, 0); \
  }

#define MFMA4(AREG, ROW)                                                           \
  acc[ROW][0] = __builtin_amdgcn_mfma_f32_16x16x32_f16(AREG, b0, acc[ROW][0], 0, 0, 0); \
  acc[ROW][1] = __builtin_amdgcn_mfma_f32_16x16x32_f16(AREG, b1, acc[ROW][1], 0, 0, 0); \
  acc[ROW][2] = __builtin_amdgcn_mfma_f32_16x16x32_f16(AREG, b2, acc[ROW][2], 0, 0, 0); \
  acc[ROW][3] = __builtin_amdgcn_mfma_f32_16x16x32_f16(AREG, b3, acc[ROW][3], 0, 0, 0);

#define PHASE(ABASE, BBASE, MH, STG, VMW)                                          \
  {                                                                                \
    f16x8 a0 = *(const f16x8*)((ABASE) + (wm * 128 + (MH) * 64 +  0 + l15) * 64 + swz); \
    f16x8 a1 = *(const f16x8*)((ABASE) + (wm * 128 + (MH) * 64 + 16 + l15) * 64 + swz); \
    f16x8 a2 = *(const f16x8*)((ABASE) + (wm * 128 + (MH) * 64 + 32 + l15) * 64 + swz); \
    f16x8 a3 = *(const f16x8*)((ABASE) + (wm * 128 + (MH) * 64 + 48 + l15) * 64 + swz); \
    if ((MH) == 0) {                                                               \
      b0 = *(const f16x8*)((BBASE) + (wn * 64 +  0 + l15) * 64 + swz);             \
      b1 = *(const f16x8*)((BBASE) + (wn * 64 + 16 + l15) * 64 + swz);             \
      b2 = *(const f16x8*)((BBASE) + (wn * 64 + 32 + l15) * 64 + swz);             \
      b3 = *(const f16x8*)((BBASE) + (wn * 64 + 48 + l15) * 64 + swz);             \
    }                                                                              \
    STG;                                                                           \
    __builtin_amdgcn_s_barrier();                                                  \
    asm volatile("s_waitcnt lgkmcnt(0)" ::: "memory");                             \
    __builtin_amdgcn_sched_barrier(0);                                             \
    __builtin_amdgcn_s_setprio(1);                                                 \
    MFMA4(a0, (MH) * 4 + 0) MFMA4(a1, (MH) * 4 + 1)                                \
    MFMA4(a2, (MH) * 4 + 2) MFMA4(a3, (MH) * 4 + 3)                                \
    __builtin_amdgcn_s_setprio(0);                                                 \
    VMW;                                                                           \
    __builtin_amdgcn_s_barrier();                                                  \
  }

template <typename OutT>
__global__ __launch_bounds__(512, 2)
void gemm256(const f16* __restrict__ A, const f16* __restrict__ B,
             const float* __restrict__ bias, OutT* __restrict__ C,
             int N, int K, int ntiles_n) {
  __shared__ char lds[131072];
  const int tid = threadIdx.x;
  const int wid = tid >> 6, ln = tid & 63;
  const int l15 = ln & 15, lhi = ln >> 4;
  const int wm = wid >> 2, wn = wid & 3;
  const int srow = ln >> 2;
  const int sce = (((ln & 3) ^ ((ln >> 3) & 3)) << 3);
  const int swz = ((lhi ^ ((l15 >> 1) & 3)) << 4);

  const int nblk = gridDim.x;
  const int wg = (blockIdx.x & 7) * (nblk >> 3) + (blockIdx.x >> 3);
  const int bn = wg % ntiles_n, bm = wg / ntiles_n;
  const int m0 = bm * 256, n0 = bn * 256;

  f32x4 acc[8][4];
#pragma unroll
  for (int i = 0; i < 8; ++i)
#pragma unroll
    for (int j = 0; j < 4; ++j) acc[i][j] = (f32x4){0.f, 0.f, 0.f, 0.f};
  f16x8 b0, b1, b2, b3;

  STAGE(A, m0, 0, 0);
  STAGE(B, n0, 0, 32768);
  STAGE(A, m0, 32, 16384);
  STAGE(B, n0, 32, 49152);
  STAGE(A, m0, 64, 65536);
  STAGE(B, n0, 64, 98304);
  VM4;
  __builtin_amdgcn_s_barrier();

  for (int i = 0; i < 7; ++i) {
    const int cT1k1 = (2 * i + 1) * 64 + 32;
    const int cT2k0 = (2 * i + 2) * 64;
    const int cT2k1 = cT2k0 + 32;
    const int cT3k0 = (2 * i + 3) * 64;
    PHASE(lds + 0,      lds + 32768,  0, STAGE(A, m0, cT1k1, 81920),  NOVM);
    PHASE(lds + 0,      lds + 32768,  1, STAGE(B, n0, cT1k1, 114688), NOVM);
    PHASE(lds + 16384,  lds + 49152,  0, STAGE(A, m0, cT2k0, 0),      NOVM);
    PHASE(lds + 16384,  lds + 49152,  1, STAGE(B, n0, cT2k0, 32768),  VM4);
    PHASE(lds + 65536,  lds + 98304,  0, STAGE(A, m0, cT2k1, 16384),  NOVM);
    PHASE(lds + 65536,  lds + 98304,  1, STAGE(B, n0, cT2k1, 49152),  NOVM);
    PHASE(lds + 81920,  lds + 114688, 0, STAGE(A, m0, cT3k0, 65536),  NOVM);
    PHASE(lds + 81920,  lds + 114688, 1, STAGE(B, n0, cT3k0, 98304),  VM4);
  }
  PHASE(lds + 0,      lds + 32768,  0, STAGE(A, m0, 15 * 64 + 32, 81920),  NOVM);
  PHASE(lds + 0,      lds + 32768,  1, STAGE(B, n0, 15 * 64 + 32, 114688), NOVM);
  PHASE(lds + 16384,  lds + 49152,  0, NOSTG, NOVM);
  PHASE(lds + 16384,  lds + 49152,  1, NOSTG, VM0);
  PHASE(lds + 65536,  lds + 98304,  0, NOSTG, NOVM);
  PHASE(lds + 65536,  lds + 98304,  1, NOSTG, NOVM);
  PHASE(lds + 81920,  lds + 114688, 0, NOSTG, NOVM);
  PHASE(lds + 81920,  lds + 114688, 1, NOSTG, NOVM);

  float bv[4];
#pragma unroll
  for (int j = 0; j < 4; ++j) bv[j] = bias[n0 + wn * 64 + j * 16 + l15];
#pragma unroll
  for (int ii = 0; ii < 8; ++ii)
#pragma unroll
    for (int j = 0; j < 4; ++j)
#pragma unroll
      for (int r = 0; r < 4; ++r) {
        int gr = m0 + wm * 128 + ii * 16 + lhi * 4 + r;
        int gc = n0 + wn * 64 + j * 16 + l15;
        C[(size_t)gr * N + gc] = (OutT)(acc[ii][j][r] + bv[j]);
      }
}

// ---------------- attention: 1 wave per (window, head), zero barriers ----------------
// LDS 16KB: K then P [0,8K), Vt [8K,16K). All global loads issued up front;
// one vmcnt(0) drain; per-wave in-order DS gives all remaining ordering.
__global__ __launch_bounds__(64)
void attn_kernel(const f16* __restrict__ qkv,        // [MTOT][3072] q|k|v
                 const f16* __restrict__ bias_t,     // f16 [16][m][n], pre-scaled log2e
                 f16* __restrict__ out) {             // [MTOT][1024]
  __shared__ char lds[16384];
  const int bh = blockIdx.x;
  const int b = bh >> 4, h = bh & 15;
  const int ln = threadIdx.x;
  const int l15 = ln & 15, lhi = ln >> 4;
  const size_t base = (size_t)b * 49;

  // --- issue K staging (8x global_load_lds) ---
  {
    int rA = ln >> 3, lc = ln & 7;
#pragma unroll
    for (int c = 0; c < 8; ++c) {
      int r = c * 8 + rA;
      int ce = (lc ^ (r & 7)) << 3;
      size_t row = base + r;
      if (row > MROW_MAX) row = MROW_MAX;
      const f16* g = qkv + row * 3072 + 1024 + h * 64 + ce;
      __builtin_amdgcn_global_load_lds(G1P(g), L3P(lds + c * 1024), 16, 0, 0);
    }
  }

  // --- issue V loads (8x b128) ---
  size_t rowv = base + ln;
  if (rowv > MROW_MAX) rowv = MROW_MAX;
  const f16* vp = qkv + rowv * 3072 + 2048 + h * 64;
  f16x8 vr[8];
#pragma unroll
  for (int j = 0; j < 8; ++j) vr[j] = *(const f16x8*)(vp + j * 8);

  // --- issue Q loads (8x b128) ---
  f16x8 qf[4][2];
#pragma unroll
  for (int t = 0; t < 4; ++t) {
    size_t row = base + t * 16 + l15;
    if (row > MROW_MAX) row = MROW_MAX;
    const f16* qp = qkv + row * 3072 + h * 64 + lhi * 8;
    qf[t][0] = *(const f16x8*)(qp);
    qf[t][1] = *(const f16x8*)(qp + 32);
  }

  // --- issue bias loads (16x f16x4): bq[i][j] = bias[m=j*16+l15][n=i*16+lhi*4 ..+4) ---
  const f16* bb = bias_t + h * 4096;
  f16x4 bq[4][4];
#pragma unroll
  for (int i = 0; i < 4; ++i)
#pragma unroll
    for (int j = 0; j < 4; ++j)
      bq[i][j] = *(const f16x4*)(bb + (j * 16 + l15) * 64 + i * 16 + lhi * 4);

  // --- V transpose into Vt (compiler waits vr) ---
#pragma unroll
  for (int d = 0; d < 64; ++d)
    *(f16*)(lds + 8192 + d * 128 + ((ln * 2) ^ ((d & 7) << 4))) = vr[d >> 3][d & 7];

  // --- single drain: K LDS deposit + all reg loads complete ---
  asm volatile("s_waitcnt vmcnt(0)" ::: "memory");
  __builtin_amdgcn_sched_barrier(0);

  // --- S = Q @ K^T (K frags from LDS) ---
  f32x4 acc[4][4];
#pragma unroll
  for (int i = 0; i < 4; ++i)
#pragma unroll
    for (int j = 0; j < 4; ++j) acc[i][j] = (f32x4){0.f, 0.f, 0.f, 0.f};
#pragma unroll
  for (int kk = 0; kk < 2; ++kk) {
    f16x8 bf[4];
#pragma unroll
    for (int t = 0; t < 4; ++t) {
      int mr = t * 16 + l15;
      int pb = (kk * 64 + lhi * 16) ^ ((mr & 7) << 4);
      bf[t] = *(const f16x8*)(lds + mr * 128 + pb);
    }
    __builtin_amdgcn_s_setprio(1);
#pragma unroll
    for (int i = 0; i < 4; ++i)
#pragma unroll
      for (int j = 0; j < 4; ++j)
        acc[i][j] = __builtin_amdgcn_mfma_f32_16x16x32_f16(qf[i][kk], bf[j], acc[i][j], 0, 0, 0);
    __builtin_amdgcn_s_setprio(0);
  }

  // --- softmax (base-2; bias already in regs); P overwrites K region ---
  const float SC = 0.125f * 1.44269504f;
#pragma unroll
  for (int i = 0; i < 4; ++i) {
#pragma unroll
    for (int r = 0; r < 4; ++r) {
      int n = i * 16 + lhi * 4 + r;
      float lv[4];
#pragma unroll
      for (int j = 0; j < 4; ++j)
        lv[j] = acc[i][j][r] * SC + (float)bq[i][j][r];
      float Mx = fmaxf(fmaxf(lv[0], lv[1]), fmaxf(lv[2], lv[3]));
#pragma unroll
      for (int off = 1; off < 16; off <<= 1) Mx = fmaxf(Mx, __shfl_xor(Mx, off));
      float s = 0.f;
#pragma unroll
      for (int j = 0; j < 4; ++j) { lv[j] = exp2f(lv[j] - Mx); s += lv[j]; }
#pragma unroll
      for (int off = 1; off < 16; off <<= 1) s += __shfl_xor(s, off);
      float inv = 1.f / s;
#pragma unroll
      for (int j = 0; j < 4; ++j) {
        int m = j * 16 + l15;
        *(f16*)(lds + n * 128 + ((m * 2) ^ ((n & 7) << 4))) = (f16)(lv[j] * inv);
      }
    }
  }
  // per-wave in-order DS: P writes retire before the P reads below

  // --- O = P @ V ---
  f32x4 o[4][4];
#pragma unroll
  for (int i = 0; i < 4; ++i)
#pragma unroll
    for (int j = 0; j < 4; ++j) o[i][j] = (f32x4){0.f, 0.f, 0.f, 0.f};
#pragma unroll
  for (int kk = 0; kk < 2; ++kk) {
    f16x8 af[4], bf[4];
#pragma unroll
    for (int t = 0; t < 4; ++t) {
      int nr = t * 16 + l15;
      int pb = (kk * 64 + lhi * 16) ^ ((nr & 7) << 4);
      af[t] = *(const f16x8*)(lds + nr * 128 + pb);
      bf[t] = *(const f16x8*)(lds + 8192 + nr * 128 + pb);
    }
    __builtin_amdgcn_s_setprio(1);
#pragma unroll
    for (int i = 0; i < 4; ++i)
#pragma unroll
      for (int j = 0; j < 4; ++j)
        o[i][j] = __builtin_amdgcn_mfma_f32_16x16x32_f16(af[i], bf[j], o[i][j], 0, 0, 0);
    __builtin_amdgcn_s_setprio(0);
  }
#pragma unroll
  for (int i = 0; i < 4; ++i)
#pragma unroll
    for (int j = 0; j < 4; ++j)
#pragma unroll
      for (int r = 0; r < 4; ++r) {
        int n = i * 16 + lhi * 4 + r;
        if (n < 49)
          out[(base + n) * 1024 + h * 64 + j * 16 + l15] = (f16)o[i][j][r];
      }
}

extern "C" void kernel_launch(void* const* d_in, const int* in_sizes, int n_in,
                              void* d_out, int out_size, void* d_ws, size_t ws_size,
                              hipStream_t stream) {
  const float* x      = (const float*)d_in[0];  // [100352][1024]
  const float* qkv_w  = (const float*)d_in[1];  // [3072][1024]
  const float* qkv_b  = (const float*)d_in[2];  // [3072]
  const float* rpb    = (const float*)d_in[3];  // [16][13][13]
  const float* proj_w = (const float*)d_in[4];  // [1024][1024]
  const float* proj_b = (const float*)d_in[5];  // [1024]
  float* out = (float*)d_out;

  char* ws = (char*)d_ws;
  f16*   x16      = (f16*)(ws);                              // 205,520,896
  f16*   wq16     = (f16*)(ws + 205520896);                  //   6,291,456
  f16*   wp16     = (f16*)(ws + 211812352);                  //   2,097,152
  f16*   qkv16    = (f16*)(ws + 213909504);                  // 616,562,688
  f16*   attn16   = (f16*)(ws + 830472192);                  // 205,520,896
  f16*   bias_t   = (f16*)(ws + 1035993088);                 //     131,072

  cvt_kernel<<<2048, 256, 0, stream>>>(x, x16, 102760448 / 4);
  cvt_kernel<<<1024, 256, 0, stream>>>(qkv_w, wq16, 3145728 / 4);
  cvt_kernel<<<512, 256, 0, stream>>>(proj_w, wp16, 1048576 / 4);
  bias_kernel<<<16, 64, 0, stream>>>(rpb, bias_t);

  // qkv = x @ qkv_w^T + qkv_b   [100352][3072] fp16   (392 x 12 tiles)
  gemm256<f16><<<4704, 512, 0, stream>>>(x16, wq16, qkv_b, qkv16, 3072, 1024, 12);
  // attention: 1 wave per (window, head), latency-optimized
  attn_kernel<<<2048 * 16, 64, 0, stream>>>(qkv16, bias_t, attn16);
  // out = attn @ proj_w^T + proj_b   [100352][1024] fp32  (392 x 4 tiles)
  gemm256<float><<<1568, 512, 0, stream>>>(attn16, wp16, proj_b, out, 1024, 1024, 4);
}